// Round 5
// baseline (14.006 us; speedup 1.0000x reference)
//
#include <hip/hip_runtime.h>

#define HH 256
#define WW 256
#define SS 15
#define NB 64

// Single-instruction transcendentals (v_log_f32 = log2, v_exp_f32 = exp2).
__device__ __forceinline__ float alog2(float x) {
    float r; asm("v_log_f32 %0, %1" : "=v"(r) : "v"(x)); return r;
}
__device__ __forceinline__ float aexp2(float x) {
    float r; asm("v_exp_f32 %0, %1" : "=v"(r) : "v"(x)); return r;
}

// grid = 64 batches x 16 blocks, block = 256 thr = 4 waves.
// Each wave owns 1024 contiguous px = 4 full columns (x-major flatten:
// out[b][i][j] = position (y=j, x=i)). Lane l covers rows y=4l..4l+3 of all
// 4 columns -> dy^2 computed once serves 4 columns; dx^2 per column is
// wave-uniform -> exact per-column cull (canvas==0 whenever d>=w).
// Epilogue: (sqrt(m)/w+eps)^af -> exp2(0.5*af*log2(m) - af*log2(w)); eps
// dropped (worst dev ~1.6e-3 << 2e-2); p=exp2>=0 so upper clamp redundant.
__global__ __launch_bounds__(256) void CurveGraphic2d_kernel(
    const float* __restrict__ inputs,   // [64,4,2] normalized (y,x)
    const float* __restrict__ widths,   // [64]
    const float* __restrict__ aaf,      // [64]
    float* __restrict__ out)            // [64,256,256]
{
    const int b      = blockIdx.x >> 4;            // 16 blocks per batch
    const int blk    = blockIdx.x & 15;
    const int tid    = threadIdx.x;
    const int lane   = tid & 63;
    const int region = blk * 4 + (tid >> 6);       // 0..63; columns 4r..4r+3

    __shared__ float2 sp[SS];                      // (sy, sx)

    if (tid < SS) {
        float t = (float)tid * (1.0f / (float)(SS - 1));
        float u = 1.0f - t;
        float b0 = u * u * u;
        float b1 = 3.0f * t * u * u;
        float b2 = 3.0f * t * t * u;
        float b3 = t * t * t;
        const float* kp = inputs + b * 8;          // [4][2] (y,x) pairs
        float syv = 256.0f * (b0 * kp[0] + b1 * kp[2] + b2 * kp[4] + b3 * kp[6]);
        float sxv = 256.0f * (b0 * kp[1] + b1 * kp[3] + b2 * kp[5] + b3 * kp[7]);
        sp[tid] = make_float2(syv, sxv);
    }
    __syncthreads();

    const float w  = widths[b];
    const float w2 = w * w;

    const float x0 = (float)(region * 4);
    const float y0 = (float)(lane * 4);

    float m[4][4];
    #pragma unroll
    for (int c = 0; c < 4; ++c)
        #pragma unroll
        for (int k = 0; k < 4; ++k) m[c][k] = 1e30f;

    #pragma unroll
    for (int s = 0; s < SS; ++s) {
        float2 pp  = sp[s];                        // broadcast ds_read_b64
        float sys  = pp.x, sxs = pp.y;
        float d0   = x0 - sxs;
        float d1   = d0 + 1.0f, d2 = d0 + 2.0f, d3 = d0 + 3.0f;
        float dxx0 = d0 * d0, dxx1 = d1 * d1, dxx2 = d2 * d2, dxx3 = d3 * d3;
        float mn   = fminf(fminf(dxx0, dxx1), fminf(dxx2, dxx3));
        if (mn < w2) {                             // wave-uniform
            float dy0 = y0 - sys;
            float dy1 = dy0 + 1.0f, dy2 = dy0 + 2.0f, dy3 = dy0 + 3.0f;
            float q0 = dy0 * dy0, q1 = dy1 * dy1, q2 = dy2 * dy2, q3 = dy3 * dy3;
            if (dxx0 < w2) {
                m[0][0] = fminf(m[0][0], q0 + dxx0);
                m[0][1] = fminf(m[0][1], q1 + dxx0);
                m[0][2] = fminf(m[0][2], q2 + dxx0);
                m[0][3] = fminf(m[0][3], q3 + dxx0);
            }
            if (dxx1 < w2) {
                m[1][0] = fminf(m[1][0], q0 + dxx1);
                m[1][1] = fminf(m[1][1], q1 + dxx1);
                m[1][2] = fminf(m[1][2], q2 + dxx1);
                m[1][3] = fminf(m[1][3], q3 + dxx1);
            }
            if (dxx2 < w2) {
                m[2][0] = fminf(m[2][0], q0 + dxx2);
                m[2][1] = fminf(m[2][1], q1 + dxx2);
                m[2][2] = fminf(m[2][2], q2 + dxx2);
                m[2][3] = fminf(m[2][3], q3 + dxx2);
            }
            if (dxx3 < w2) {
                m[3][0] = fminf(m[3][0], q0 + dxx3);
                m[3][1] = fminf(m[3][1], q1 + dxx3);
                m[3][2] = fminf(m[3][2], q2 + dxx3);
                m[3][3] = fminf(m[3][3], q3 + dxx3);
            }
        }
    }

    const float af    = aaf[b];
    const float haf   = 0.5f * af;                 // sqrt folded into the log
    const float cbias = -af * log2f(w);

    float* dst = out + (size_t)b * (HH * WW) + region * 1024 + lane * 4;

    #pragma unroll
    for (int c = 0; c < 4; ++c) {
        float4 o;
        o.x = fmaxf(1.0f - aexp2(fmaf(haf, alog2(m[c][0]), cbias)), 0.0f);
        o.y = fmaxf(1.0f - aexp2(fmaf(haf, alog2(m[c][1]), cbias)), 0.0f);
        o.z = fmaxf(1.0f - aexp2(fmaf(haf, alog2(m[c][2]), cbias)), 0.0f);
        o.w = fmaxf(1.0f - aexp2(fmaf(haf, alog2(m[c][3]), cbias)), 0.0f);
        *reinterpret_cast<float4*>(dst + c * 256) = o;
    }
}

extern "C" void kernel_launch(void* const* d_in, const int* in_sizes, int n_in,
                              void* d_out, int out_size, void* d_ws, size_t ws_size,
                              hipStream_t stream) {
    const float* inputs = (const float*)d_in[0];
    const float* widths = (const float*)d_in[1];
    const float* aaf    = (const float*)d_in[2];
    float* out = (float*)d_out;

    const int blocks = NB * 16;                    // 1024 blocks, 4096 waves
    CurveGraphic2d_kernel<<<blocks, 256, 0, stream>>>(inputs, widths, aaf, out);
}

// Round 6
// 11.227 us; speedup vs baseline: 1.2475x; 1.2475x over previous
//
#include <hip/hip_runtime.h>

#define HH 256
#define WW 256
#define SS 15
#define NB 64

// Single-instruction transcendentals (v_log_f32 = log2, v_exp_f32 = exp2).
__device__ __forceinline__ float alog2(float x) {
    float r; asm("v_log_f32 %0, %1" : "=v"(r) : "v"(x)); return r;
}
__device__ __forceinline__ float aexp2(float x) {
    float r; asm("v_exp_f32 %0, %1" : "=v"(r) : "v"(x)); return r;
}

// Best-measured structure (round 3) + validated micro-trims.
// grid = 64 batches x 64 blocks, block = 256 thr = 4 waves; each thread owns
// 4 contiguous px, each wave = 1 full column (x-major flatten: out[b][i][j]
// is position (y=j, x=i)) -> dx is wave-uniform.
// Exact culls (canvas==0 whenever min_dist >= w, since clip(1-(d/w)^af)<=0):
//   - sample with dx^2 >= w^2 contributes nothing -> skipped (execz)
//   - all samples culled -> whole column zero -> store zeros, return.
// Epilogue: (sqrt(m)/w+eps)^af -> exp2(0.5*af*log2(m) - af*log2(w)); eps
// dropped (worst dev ~1.6e-3 << 2e-2); p=exp2>=0 so upper clamp redundant.
__global__ __launch_bounds__(256) void CurveGraphic2d_kernel(
    const float* __restrict__ inputs,   // [64,4,2] normalized (y,x)
    const float* __restrict__ widths,   // [64]
    const float* __restrict__ aaf,      // [64]
    float* __restrict__ out)            // [64,256,256]
{
    const int b     = blockIdx.x >> 6;        // 64 blocks per batch
    const int chunk = blockIdx.x & 63;
    const int tid   = threadIdx.x;

    __shared__ float2 sp[SS];                 // (sy, sx)

    if (tid < SS) {
        float t = (float)tid * (1.0f / (float)(SS - 1));
        float u = 1.0f - t;
        // K=4 cubic Bernstein basis
        float b0 = u * u * u;
        float b1 = 3.0f * t * u * u;
        float b2 = 3.0f * t * t * u;
        float b3 = t * t * t;
        const float* kp = inputs + b * 8;     // [4][2] = (y,x) pairs
        float syv = 256.0f * (b0 * kp[0] + b1 * kp[2] + b2 * kp[4] + b3 * kp[6]);
        float sxv = 256.0f * (b0 * kp[1] + b1 * kp[3] + b2 * kp[5] + b3 * kp[7]);
        sp[tid] = make_float2(syv, sxv);
    }
    __syncthreads();

    const float w  = widths[b];
    const float w2 = w * w;

    const int base = chunk * 1024 + tid * 4;  // offset within this image
    const int i = base >> 8;                   // row index  (= x coord)
    const int j = base & 255;                  // col index  (= y coord)
    const float x  = (float)i;
    const float y0 = (float)j;

    float* dst = out + (size_t)b * (HH * WW) + base;

    // --- pass 1: dx^2 per sample (wave-uniform), sy cached to registers ---
    float dxx[SS], syr[SS];
    float minv = 1e30f;
    #pragma unroll
    for (int s = 0; s < SS; ++s) {
        float2 pp = sp[s];                     // one broadcast ds_read_b64
        syr[s] = pp.x;
        float dx = x - pp.y;
        dxx[s] = dx * dx;
        minv = fminf(minv, dxx[s]);
    }

    if (minv >= w2) {                          // whole column zero (uniform)
        *reinterpret_cast<float4*>(dst) = make_float4(0.f, 0.f, 0.f, 0.f);
        return;
    }

    // --- pass 2: min distance over surviving samples ---
    float m0 = 1e30f, m1 = 1e30f, m2 = 1e30f, m3 = 1e30f;
    #pragma unroll
    for (int s = 0; s < SS; ++s) {
        if (dxx[s] < w2) {                     // wave-uniform branch
            float sys = syr[s];
            float dy0 = y0          - sys;
            float dy1 = (y0 + 1.0f) - sys;
            float dy2 = (y0 + 2.0f) - sys;
            float dy3 = (y0 + 3.0f) - sys;
            m0 = fminf(m0, fmaf(dy0, dy0, dxx[s]));
            m1 = fminf(m1, fmaf(dy1, dy1, dxx[s]));
            m2 = fminf(m2, fmaf(dy2, dy2, dxx[s]));
            m3 = fminf(m3, fmaf(dy3, dy3, dxx[s]));
        }
    }

    const float af    = aaf[b];
    const float haf   = 0.5f * af;             // sqrt folded into the log
    const float cbias = -af * log2f(w);

    float4 o;
    o.x = fmaxf(1.0f - aexp2(fmaf(haf, alog2(m0), cbias)), 0.0f);
    o.y = fmaxf(1.0f - aexp2(fmaf(haf, alog2(m1), cbias)), 0.0f);
    o.z = fmaxf(1.0f - aexp2(fmaf(haf, alog2(m2), cbias)), 0.0f);
    o.w = fmaxf(1.0f - aexp2(fmaf(haf, alog2(m3), cbias)), 0.0f);

    *reinterpret_cast<float4*>(dst) = o;
}

extern "C" void kernel_launch(void* const* d_in, const int* in_sizes, int n_in,
                              void* d_out, int out_size, void* d_ws, size_t ws_size,
                              hipStream_t stream) {
    const float* inputs = (const float*)d_in[0];
    const float* widths = (const float*)d_in[1];
    const float* aaf    = (const float*)d_in[2];
    float* out = (float*)d_out;

    const int blocks = NB * 64;                // 4096 blocks, 16384 waves
    CurveGraphic2d_kernel<<<blocks, 256, 0, stream>>>(inputs, widths, aaf, out);
}